// Round 1
// 1632.192 us; speedup vs baseline: 1.0834x; 1.0834x over previous
//
#include <hip/hip_runtime.h>
#include <stdint.h>

typedef _Float16 half_t;
typedef half_t half2v __attribute__((ext_vector_type(2)));
typedef half_t half8  __attribute__((ext_vector_type(8)));
typedef float  f32x4v __attribute__((ext_vector_type(4)));

typedef __attribute__((address_space(1))) void as1_void;
typedef __attribute__((address_space(3))) void as3_void;
#define GLOAD_LDS16(gp, lp) \
  __builtin_amdgcn_global_load_lds((as1_void*)(gp), (as3_void*)(lp), 16, 0, 0)

// B=4096 REPR=39200 FEAT=256 HID=1024 GATE=256 MHID=256 E=32 K=4 SDIM=24 ADIM=7
constexpr int MAXTILES = 288;
constexpr int SLOTCAP  = MAXTILES * 64;
constexpr float LO_SCALE = 2048.f;      // 2^11 keeps W_lo/A_lo in fp16-normal range
constexpr float LO_INV   = 1.f / 2048.f;

// ---------------- workspace layout (bytes) ----------------
constexpr size_t PLANE_TRUNK = (size_t)256 * 39200;          // elements per plane
constexpr size_t PLANE_SMALL = (size_t)262144;               // 256x1024 or 1024x256
constexpr size_t OFF_WT_TRUNK = 0;                                   // 2 planes fp16
constexpr size_t OFF_WT_SE2 = OFF_WT_TRUNK + PLANE_TRUNK * 2 * 2;    // 40,140,800
constexpr size_t OFF_WT_FU1 = OFF_WT_SE2 + PLANE_SMALL * 2 * 2;
constexpr size_t OFF_WT_FU2 = OFF_WT_FU1 + PLANE_SMALL * 2 * 2;
constexpr size_t OFF_WT_P1  = OFF_WT_FU2 + PLANE_SMALL * 2 * 2;
constexpr size_t OFF_WT_G1  = OFF_WT_P1  + PLANE_SMALL * 2 * 2;
constexpr size_t OFF_WT_E1  = OFF_WT_G1  + PLANE_SMALL * 2 * 2;      // fp16 single
constexpr size_t OFF_WT_E2  = OFF_WT_E1  + (size_t)32 * 262144 * 2;
constexpr size_t OFF_PART   = OFF_WT_E2  + (size_t)32 * 262144 * 2;
constexpr size_t SZ_PART    = (size_t)12 * 4096 * 256 * 4;           // 50.3 MB
constexpr size_t OFF_YBUF   = OFF_PART;   // fp16 18432x1024 = 37.7MB, disjoint in time
constexpr size_t OFF_S1     = OFF_PART + SZ_PART;                    // fp32 4096x1024
constexpr size_t OFF_H1     = OFF_S1;     // alias: S1 dead before H1 written
constexpr size_t OFF_SOUT   = OFF_S1   + (size_t)4096 * 1024 * 4;
constexpr size_t OFF_HBUF   = OFF_SOUT + (size_t)4096 * 256 * 4;     // fp32
constexpr size_t OFF_H2     = OFF_HBUF + (size_t)4096 * 256 * 4;
constexpr size_t OFF_XBUF   = OFF_H2   + (size_t)4096 * 256 * 4;     // fp32 4096x1024
constexpr size_t OFF_GBUF   = OFF_XBUF + (size_t)4096 * 1024 * 4;
constexpr size_t OFF_LOGITS = OFF_GBUF + (size_t)4096 * 256 * 4;
constexpr size_t OFF_RTI    = OFF_LOGITS + (size_t)4096 * 32 * 4;
constexpr size_t OFF_RTW    = OFF_RTI  + (size_t)4096 * 4 * 4;
constexpr size_t OFF_CTRL   = OFF_RTW  + (size_t)4096 * 4 * 4;
constexpr size_t SZ_CTRL    = 4096;
constexpr size_t OFF_SLOTB  = OFF_CTRL + SZ_CTRL;
constexpr size_t OFF_R2S    = OFF_SLOTB + (size_t)SLOTCAP * 4;
constexpr size_t OFF_H1E    = OFF_R2S  + (size_t)4096 * 4 * 4;       // fp16 18432x256
// total ~= 177 MB

// =====================================================================
// Weight convert pre-pass: fp32 [K][N] -> fp16 [N][Kp]; hi/lo planes for
// the gating chain, single plane for experts.
// =====================================================================
__global__ __launch_bounds__(256) void cvt_k(
    const float* __restrict__ trunk_w, const float* __restrict__ se2_w,
    const float* __restrict__ fu1_w,  const float* __restrict__ fu2_w,
    const float* __restrict__ p1_w,   const float* __restrict__ g1_w,
    const float* __restrict__ e1_w,   const float* __restrict__ e2_w,
    char* __restrict__ ws)
{
    __shared__ float t[32][33];
    int id = blockIdx.x;
    const float* src; half_t* dh; int N, Kp, kt, nt; size_t plane;
    if (id < 9800)       { src = trunk_w; dh = (half_t*)(ws + OFF_WT_TRUNK); plane = PLANE_TRUNK; N=256;  Kp=39200; kt=id>>3; nt=id&7; }
    else if (id < 10056) { int r=id-9800;  src = se2_w; dh=(half_t*)(ws+OFF_WT_SE2); plane=PLANE_SMALL; N=256;  Kp=1024; kt=r>>3; nt=r&7; }
    else if (id < 10312) { int r=id-10056; src = fu1_w; dh=(half_t*)(ws+OFF_WT_FU1); plane=PLANE_SMALL; N=1024; Kp=256;  kt=r>>5; nt=r&31; }
    else if (id < 10568) { int r=id-10312; src = fu2_w; dh=(half_t*)(ws+OFF_WT_FU2); plane=PLANE_SMALL; N=256;  Kp=1024; kt=r>>3; nt=r&7; }
    else if (id < 10824) { int r=id-10568; src = p1_w;  dh=(half_t*)(ws+OFF_WT_P1);  plane=PLANE_SMALL; N=1024; Kp=256;  kt=r>>5; nt=r&31; }
    else if (id < 11080) { int r=id-10824; src = g1_w;  dh=(half_t*)(ws+OFF_WT_G1);  plane=PLANE_SMALL; N=256;  Kp=1024; kt=r>>3; nt=r&7; }
    else if (id < 19272) { int r=id-11080; int e=r>>8; int rr=r&255;
        src = e1_w + (size_t)e*262144; dh = (half_t*)(ws+OFF_WT_E1) + (size_t)e*262144;
        plane = 0; N=256; Kp=1024; kt=rr>>3; nt=rr&7; }
    else                 { int r=id-19272; int e=r>>8; int rr=r&255;
        src = e2_w + (size_t)e*262144; dh = (half_t*)(ws+OFF_WT_E2) + (size_t)e*262144;
        plane = 0; N=1024; Kp=256; kt=rr>>5; nt=rr&31; }

    int k0 = kt * 32, n0 = nt * 32;
    int tx = threadIdx.x & 31, ty = threadIdx.x >> 5;
#pragma unroll
    for (int i = 0; i < 4; ++i) {
        int r = i * 8 + ty;
        t[tx][r] = src[(size_t)(k0 + r) * N + (n0 + tx)];
    }
    __syncthreads();
#pragma unroll
    for (int i = 0; i < 4; ++i) {
        int rn = i * 8 + ty;
        float v = t[rn][tx];
        size_t di = (size_t)(n0 + rn) * Kp + (k0 + tx);
        half_t hv = (half_t)v;
        dh[di] = hv;
        if (plane) dh[di + plane] = (half_t)((v - (float)hv) * LO_SCALE);
    }
}

// =====================================================================
// Precision GEMM (gating chain): A fp32 -> fp16 hi/lo in LDS; W hi/lo
// fp16 planes; 3 MFMAs into 2 accumulators; ~fp32-accurate.
// 2-phase pipelined: stage tile k+1 (gloads + cvt) before computing
// tile k; one counted-vmcnt barrier per K-step. A reg-prefetch rides
// across the barrier (vmcnt(2)).
// =====================================================================
template<int ACT, int PARTIAL>
__global__ __launch_bounds__(256) void gemm_prec(
    const float* __restrict__ A, const half_t* __restrict__ Wt,
    const float* __restrict__ bias, void* __restrict__ Outp,
    int KpA, int KpW, int ksteps, int NoutStride, size_t planeB)
{
    constexpr int BUF = (64 + 64 + 256 + 256) * 64;   // 40960 per stage
    __shared__ __attribute__((aligned(16))) char lds[2 * BUF];
    const int tid = threadIdx.x;
    const int lane = tid & 63, wid = tid >> 6;
    const int mrow = lane & 15, quad = lane >> 4;

    const int m0 = blockIdx.x * 64;
    int n0, ks0, ks1;
    if (PARTIAL) {
        n0 = 0;
        int S = gridDim.y;
        ks0 = (int)(((long)blockIdx.y * ksteps) / S);
        ks1 = (int)(((long)(blockIdx.y + 1) * ksteps) / S);
    } else { n0 = blockIdx.y * 256; ks0 = 0; ks1 = ksteps; }

    const int ar = tid >> 2, ap = tid & 3;
    const int ac = ap ^ ((ar >> 1) & 3);
    const float* a32 = A + (size_t)(m0 + ar) * KpA + ac * 8;

    const half_t* bsrcH[4];
    int bdst[4];
#pragma unroll
    for (int j = 0; j < 4; ++j) {
        int lin = j * 256 + tid;
        int br = lin >> 2, bp = lin & 3;
        int bc = bp ^ ((br >> 1) & 3);
        bsrcH[j] = Wt + (size_t)(n0 + br) * KpW + bc * 8;
        bdst[j] = lin * 16;
    }

    int aoff[4], boff[4];
#pragma unroll
    for (int mt = 0; mt < 4; ++mt) {
        int r = mt * 16 + mrow;
        aoff[mt] = r * 64 + ((quad ^ ((r >> 1) & 3)) << 4);
    }
#pragma unroll
    for (int nt = 0; nt < 4; ++nt) {
        int r = wid * 64 + nt * 16 + mrow;
        boff[nt] = r * 64 + ((quad ^ ((r >> 1) & 3)) << 4);
    }

    f32x4v zero4 = {0.f, 0.f, 0.f, 0.f};
    f32x4v accM[4][4], accC[4][4];
#pragma unroll
    for (int mt = 0; mt < 4; ++mt)
#pragma unroll
        for (int nt = 0; nt < 4; ++nt) { accM[mt][nt] = zero4; accC[mt][nt] = zero4; }

    f32x4v pf0 = *(const f32x4v*)(a32 + ks0 * 32);
    f32x4v pf1 = *(const f32x4v*)(a32 + ks0 * 32 + 4);

    // ---- prologue: stage ks0 into buffer 0 ----
    {
        const int kk = ks0 * 32;
#pragma unroll
        for (int j = 0; j < 4; ++j) {
            GLOAD_LDS16(bsrcH[j] + kk, lds + 8192 + bdst[j]);
            GLOAD_LDS16(bsrcH[j] + planeB + kk, lds + 8192 + 16384 + bdst[j]);
        }
        half8 ah, al;
#pragma unroll
        for (int u = 0; u < 4; ++u) {
            float v0 = pf0[u], v1 = pf1[u];
            half_t h0 = (half_t)v0, h1 = (half_t)v1;
            ah[u] = h0; ah[4 + u] = h1;
            al[u]     = (half_t)((v0 - (float)h0) * LO_SCALE);
            al[4 + u] = (half_t)((v1 - (float)h1) * LO_SCALE);
        }
        *(half8*)(lds + tid * 16) = ah;
        *(half8*)(lds + 4096 + tid * 16) = al;
        int kn = (ks0 + 1 < ks1) ? ks0 + 1 : ks0;
        pf0 = *(const f32x4v*)(a32 + kn * 32);
        pf1 = *(const f32x4v*)(a32 + kn * 32 + 4);
    }
    asm volatile("s_waitcnt vmcnt(2) lgkmcnt(0)" ::: "memory");
    __builtin_amdgcn_s_barrier();

    int cur = 0;
    for (int ks = ks0; ks < ks1; ++ks) {
        char* cb = lds + cur * BUF;
        char* nb = lds + (cur ^ 1) * BUF;
        if (ks + 1 < ks1) {
            const int kk = (ks + 1) * 32;
#pragma unroll
            for (int j = 0; j < 4; ++j) {
                GLOAD_LDS16(bsrcH[j] + kk, nb + 8192 + bdst[j]);
                GLOAD_LDS16(bsrcH[j] + planeB + kk, nb + 8192 + 16384 + bdst[j]);
            }
            half8 ah, al;
#pragma unroll
            for (int u = 0; u < 4; ++u) {
                float v0 = pf0[u], v1 = pf1[u];
                half_t h0 = (half_t)v0, h1 = (half_t)v1;
                ah[u] = h0; ah[4 + u] = h1;
                al[u]     = (half_t)((v0 - (float)h0) * LO_SCALE);
                al[4 + u] = (half_t)((v1 - (float)h1) * LO_SCALE);
            }
            *(half8*)(nb + tid * 16) = ah;
            *(half8*)(nb + 4096 + tid * 16) = al;
            int kn = (ks + 2 < ks1) ? ks + 2 : ks + 1;
            pf0 = *(const f32x4v*)(a32 + kn * 32);
            pf1 = *(const f32x4v*)(a32 + kn * 32 + 4);
        }
        half8 fah[4], fal[4], fbh[4], fbl[4];
#pragma unroll
        for (int mt = 0; mt < 4; ++mt) {
            fah[mt] = *(const half8*)(cb + aoff[mt]);
            fal[mt] = *(const half8*)(cb + 4096 + aoff[mt]);
        }
#pragma unroll
        for (int nt = 0; nt < 4; ++nt) {
            fbh[nt] = *(const half8*)(cb + 8192 + boff[nt]);
            fbl[nt] = *(const half8*)(cb + 8192 + 16384 + boff[nt]);
        }
#pragma unroll
        for (int mt = 0; mt < 4; ++mt)
#pragma unroll
            for (int nt = 0; nt < 4; ++nt) {
                accM[mt][nt] = __builtin_amdgcn_mfma_f32_16x16x32_f16(fah[mt], fbh[nt], accM[mt][nt], 0, 0, 0);
                accC[mt][nt] = __builtin_amdgcn_mfma_f32_16x16x32_f16(fal[mt], fbh[nt], accC[mt][nt], 0, 0, 0);
                accC[mt][nt] = __builtin_amdgcn_mfma_f32_16x16x32_f16(fah[mt], fbl[nt], accC[mt][nt], 0, 0, 0);
            }
        asm volatile("s_waitcnt vmcnt(2) lgkmcnt(0)" ::: "memory");
        __builtin_amdgcn_s_barrier();
        cur ^= 1;
    }

    if (PARTIAL) {
        float* po = (float*)Outp + (size_t)blockIdx.y * 4096 * 256;
#pragma unroll
        for (int mt = 0; mt < 4; ++mt)
#pragma unroll
            for (int nt = 0; nt < 4; ++nt) {
                int col = wid * 64 + nt * 16 + mrow;
#pragma unroll
                for (int r = 0; r < 4; ++r) {
                    int row = m0 + mt * 16 + quad * 4 + r;
                    po[(size_t)row * 256 + col] = accM[mt][nt][r] + accC[mt][nt][r] * LO_INV;
                }
            }
    } else {
        float* fo = (float*)Outp;
#pragma unroll
        for (int nt = 0; nt < 4; ++nt) {
            int col = n0 + wid * 64 + nt * 16 + mrow;
            float bv = bias[col];
#pragma unroll
            for (int mt = 0; mt < 4; ++mt)
#pragma unroll
                for (int r = 0; r < 4; ++r) {
                    int row = m0 + mt * 16 + quad * 4 + r;
                    float v = accM[mt][nt][r] + accC[mt][nt][r] * LO_INV + bv;
                    if (ACT == 1) v = fmaxf(v, 0.f);
                    fo[(size_t)row * NoutStride + col] = v;
                }
        }
    }
}

// =====================================================================
// Fast fp16 GEMM (expert path). MODE: 1 moe-gatherA(fp32 A), 2 moe-directA.
// Same 2-phase double-buffered schedule as gemm_prec.
// =====================================================================
template<int AF32, int MODE, int ACT>
__global__ __launch_bounds__(256) void gemm_fast(
    const void* __restrict__ Aptr, const half_t* __restrict__ Wt0,
    const float* __restrict__ bias0, half_t* __restrict__ Outp,
    int KpA, int KpW, int ksteps, int NoutStride,
    const int* __restrict__ slotb, const int* __restrict__ t2e,
    const int* __restrict__ ntp, int wtStride, int biasStride)
{
    constexpr int BUF = (64 + 256) * 64;   // 20480 per stage
    __shared__ __attribute__((aligned(16))) char lds[2 * BUF];
    const int tid = threadIdx.x;
    const int lane = tid & 63, wid = tid >> 6;
    const int mrow = lane & 15, quad = lane >> 4;

    if ((int)blockIdx.x >= *ntp) return;
    int e = t2e[blockIdx.x];
    const int m0 = blockIdx.x * 64;
    const int n0 = (MODE == 2) ? blockIdx.y * 256 : 0;
    const half_t* wt = Wt0 + (size_t)e * wtStride;
    const float* bias = bias0 + (size_t)e * biasStride;

    const int ar = tid >> 2, ap = tid & 3;
    const int ac = ap ^ ((ar >> 1) & 3);
    long arow;
    if (MODE == 1) { int b = slotb[m0 + ar]; arow = (b < 0) ? 0 : b; }
    else arow = m0 + ar;
    const float*  a32 = (const float*)Aptr  + (size_t)arow * KpA + ac * 8;
    const half_t* a16 = (const half_t*)Aptr + (size_t)arow * KpA + ac * 8;

    const half_t* bsrc[4];
    int bdst[4];
#pragma unroll
    for (int j = 0; j < 4; ++j) {
        int lin = j * 256 + tid;
        int br = lin >> 2, bp = lin & 3;
        int bc = bp ^ ((br >> 1) & 3);
        bsrc[j] = wt + (size_t)(n0 + br) * KpW + bc * 8;
        bdst[j] = lin * 16;
    }

    int aoff[4], boff[4];
#pragma unroll
    for (int mt = 0; mt < 4; ++mt) {
        int r = mt * 16 + mrow;
        aoff[mt] = r * 64 + ((quad ^ ((r >> 1) & 3)) << 4);
    }
#pragma unroll
    for (int nt = 0; nt < 4; ++nt) {
        int r = wid * 64 + nt * 16 + mrow;
        boff[nt] = r * 64 + ((quad ^ ((r >> 1) & 3)) << 4);
    }

    f32x4v zero4 = {0.f, 0.f, 0.f, 0.f};
    f32x4v acc[4][4];
#pragma unroll
    for (int mt = 0; mt < 4; ++mt)
#pragma unroll
        for (int nt = 0; nt < 4; ++nt) acc[mt][nt] = zero4;

    f32x4v pf0 = zero4, pf1 = zero4;
    if (AF32) { pf0 = *(const f32x4v*)(a32); pf1 = *(const f32x4v*)(a32 + 4); }

    // ---- prologue: stage ks=0 into buffer 0 ----
    {
        if (!AF32) GLOAD_LDS16(a16, lds + tid * 16);
#pragma unroll
        for (int j = 0; j < 4; ++j) GLOAD_LDS16(bsrc[j], lds + 4096 + bdst[j]);
        if (AF32) {
            half8 av;
#pragma unroll
            for (int u = 0; u < 4; ++u) { av[u] = (half_t)pf0[u]; av[4 + u] = (half_t)pf1[u]; }
            *(half8*)(lds + tid * 16) = av;
            int kn = (1 < ksteps) ? 1 : 0;
            pf0 = *(const f32x4v*)(a32 + kn * 32);
            pf1 = *(const f32x4v*)(a32 + kn * 32 + 4);
        }
    }
    if (AF32) asm volatile("s_waitcnt vmcnt(2) lgkmcnt(0)" ::: "memory");
    else      asm volatile("s_waitcnt vmcnt(0) lgkmcnt(0)" ::: "memory");
    __builtin_amdgcn_s_barrier();

    int cur = 0;
    for (int ks = 0; ks < ksteps; ++ks) {
        char* cb = lds + cur * BUF;
        char* nb = lds + (cur ^ 1) * BUF;
        if (ks + 1 < ksteps) {
            const int kk = (ks + 1) * 32;
            if (!AF32) GLOAD_LDS16(a16 + kk, nb + tid * 16);
#pragma unroll
            for (int j = 0; j < 4; ++j) GLOAD_LDS16(bsrc[j] + kk, nb + 4096 + bdst[j]);
            if (AF32) {
                half8 av;
#pragma unroll
                for (int u = 0; u < 4; ++u) { av[u] = (half_t)pf0[u]; av[4 + u] = (half_t)pf1[u]; }
                *(half8*)(nb + tid * 16) = av;
                int kn = (ks + 2 < ksteps) ? ks + 2 : ks + 1;
                pf0 = *(const f32x4v*)(a32 + kn * 32);
                pf1 = *(const f32x4v*)(a32 + kn * 32 + 4);
            }
        }
        half8 afr[4], bfr[4];
#pragma unroll
        for (int mt = 0; mt < 4; ++mt) afr[mt] = *(const half8*)(cb + aoff[mt]);
#pragma unroll
        for (int nt = 0; nt < 4; ++nt) bfr[nt] = *(const half8*)(cb + 4096 + boff[nt]);
#pragma unroll
        for (int mt = 0; mt < 4; ++mt)
#pragma unroll
            for (int nt = 0; nt < 4; ++nt)
                acc[mt][nt] = __builtin_amdgcn_mfma_f32_16x16x32_f16(afr[mt], bfr[nt], acc[mt][nt], 0, 0, 0);
        if (AF32) asm volatile("s_waitcnt vmcnt(2) lgkmcnt(0)" ::: "memory");
        else      asm volatile("s_waitcnt vmcnt(0) lgkmcnt(0)" ::: "memory");
        __builtin_amdgcn_s_barrier();
        cur ^= 1;
    }

#pragma unroll
    for (int nt = 0; nt < 4; ++nt) {
        int col = n0 + wid * 64 + nt * 16 + mrow;
        float bv = bias[col];
#pragma unroll
        for (int mt = 0; mt < 4; ++mt)
#pragma unroll
            for (int r = 0; r < 4; ++r) {
                int row = m0 + mt * 16 + quad * 4 + r;
                float v = acc[mt][nt][r] + bv;
                if (ACT == 1) v = fmaxf(v, 0.f);
                Outp[(size_t)row * NoutStride + col] = (half_t)v;
            }
    }
}

// =====================================================================
// Split-K(4) reduce + bias + optional relu, fp32 out
// =====================================================================
template<int ACT>
__global__ __launch_bounds__(256) void reduce4_k(const float* __restrict__ part,
    const float* __restrict__ bias, float* __restrict__ outp)
{
    size_t i = ((size_t)blockIdx.x * 256 + threadIdx.x) * 4;
    f32x4v v = *(const f32x4v*)(part + i);
    v += *(const f32x4v*)(part + (size_t)1 * 4096 * 256 + i);
    v += *(const f32x4v*)(part + (size_t)2 * 4096 * 256 + i);
    v += *(const f32x4v*)(part + (size_t)3 * 4096 * 256 + i);
    int col = (int)(i & 255);
    v += *(const f32x4v*)(bias + col);
    if (ACT) {
#pragma unroll
        for (int u = 0; u < 4; ++u) v[u] = fmaxf(v[u], 0.f);
    }
    *(f32x4v*)(outp + i) = v;
}

// =====================================================================
// sensor layer1 fp32 VALU: S1 = relu(obs_sensor @ se1_w + b), K=24
// =====================================================================
__global__ __launch_bounds__(256) void se1_k(const float* __restrict__ os,
    const float* __restrict__ w, const float* __restrict__ b, float* __restrict__ out)
{
    __shared__ float lo[4][24];
    int r0 = blockIdx.x * 4;
    int t = threadIdx.x;
    if (t < 96) { int r = t / 24, k = t % 24; lo[r][k] = os[(size_t)(r0 + r) * 24 + k]; }
    __syncthreads();
    int c0 = t * 4;
    f32x4v acc[4];
    f32x4v bv = *(const f32x4v*)(b + c0);
#pragma unroll
    for (int r = 0; r < 4; ++r) acc[r] = bv;
    for (int k = 0; k < 24; ++k) {
        f32x4v wv = *(const f32x4v*)(w + (size_t)k * 1024 + c0);
#pragma unroll
        for (int r = 0; r < 4; ++r) acc[r] += lo[r][k] * wv;
    }
#pragma unroll
    for (int r = 0; r < 4; ++r) {
#pragma unroll
        for (int u = 0; u < 4; ++u) acc[r][u] = fmaxf(acc[r][u], 0.f);
        *(f32x4v*)(out + (size_t)(r0 + r) * 1024 + c0) = acc[r];
    }
}

// =====================================================================
// Trunk: reduce 8 partials + bias -> LayerNorm -> tanh -> +sensor -> fp32
// =====================================================================
__global__ __launch_bounds__(256) void lnfuse_k(const float* __restrict__ part,
    const float* __restrict__ tb, const float* __restrict__ lng, const float* __restrict__ lnb,
    const float* __restrict__ sout, float* __restrict__ hbuf)
{
    int row = blockIdx.x, col = threadIdx.x;
    size_t idx = (size_t)row * 256 + col;
    float t = tb[col];
#pragma unroll
    for (int s = 0; s < 8; ++s) t += part[(size_t)s * 4096 * 256 + idx];
    float s1 = t, s2 = t * t;
#pragma unroll
    for (int o = 32; o >= 1; o >>= 1) { s1 += __shfl_xor(s1, o, 64); s2 += __shfl_xor(s2, o, 64); }
    __shared__ float rs1[4], rs2[4];
    int wid = threadIdx.x >> 6;
    if ((threadIdx.x & 63) == 0) { rs1[wid] = s1; rs2[wid] = s2; }
    __syncthreads();
    float S1 = rs1[0] + rs1[1] + rs1[2] + rs1[3];
    float S2 = rs2[0] + rs2[1] + rs2[2] + rs2[3];
    float mu = S1 * (1.f / 256.f);
    float var = S2 * (1.f / 256.f) - mu * mu;
    float h0 = tanhf((t - mu) * rsqrtf(var + 1e-5f) * lng[col] + lnb[col]);
    hbuf[idx] = h0 + sout[idx];
}

// =====================================================================
// logits = relu-GBUF[4096,256](fp32) @ g2_w[256,32] + g2_b  (fp32 VALU)
// =====================================================================
__global__ __launch_bounds__(256) void logits_k(const float* __restrict__ g,
    const float* __restrict__ w, const float* __restrict__ bb, float* __restrict__ out)
{
    __shared__ float lw[256 * 32];
    __shared__ __attribute__((aligned(16))) float lg[8 * 256];
    int tid = threadIdx.x;
    for (int i = tid; i < 8192; i += 256) lw[i] = w[i];
    size_t base = (size_t)blockIdx.x * 8 * 256;
    *(f32x4v*)(lg + tid * 8)     = *(const f32x4v*)(g + base + tid * 8);
    *(f32x4v*)(lg + tid * 8 + 4) = *(const f32x4v*)(g + base + tid * 8 + 4);
    __syncthreads();
    int r = tid >> 5, c = tid & 31;
    const float* gr = lg + r * 256;
    float acc = bb[c];
    for (int k = 0; k < 256; k += 4) {
        acc += gr[k]   * lw[(k)   * 32 + c];
        acc += gr[k+1] * lw[(k+1) * 32 + c];
        acc += gr[k+2] * lw[(k+2) * 32 + c];
        acc += gr[k+3] * lw[(k+3) * 32 + c];
    }
    out[(size_t)blockIdx.x * 256 + tid] = acc;
}

// =====================================================================
// top-4 of 32 (ties -> lower index), softmax weights, importance + counts
// =====================================================================
__global__ __launch_bounds__(256) void topk_k(const float* __restrict__ logits,
    int* __restrict__ rti, float* __restrict__ rtw, float* __restrict__ imp, int* __restrict__ cnt)
{
    __shared__ float simp[32];
    __shared__ int scnt[32];
    int tid = threadIdx.x;
    if (tid < 32) { simp[tid] = 0.f; scnt[tid] = 0; }
    __syncthreads();
    int b = blockIdx.x * 256 + tid;
    const float* row = logits + (size_t)b * 32;
    float v0 = -1e30f, v1 = -1e30f, v2 = -1e30f, v3 = -1e30f;
    int i0 = 0, i1 = 0, i2 = 0, i3 = 0;
    for (int i = 0; i < 32; ++i) {
        float x = row[i];
        if (x > v0)      { v3=v2;i3=i2; v2=v1;i2=i1; v1=v0;i1=i0; v0=x;i0=i; }
        else if (x > v1) { v3=v2;i3=i2; v2=v1;i2=i1; v1=x;i1=i; }
        else if (x > v2) { v3=v2;i3=i2; v2=x;i2=i; }
        else if (x > v3) { v3=x;i3=i; }
    }
    float e1 = expf(v1 - v0), e2 = expf(v2 - v0), e3 = expf(v3 - v0);
    float inv = 1.f / (1.f + e1 + e2 + e3);
    rti[b*4+0] = i0; rti[b*4+1] = i1; rti[b*4+2] = i2; rti[b*4+3] = i3;
    rtw[b*4+0] = inv; rtw[b*4+1] = e1*inv; rtw[b*4+2] = e2*inv; rtw[b*4+3] = e3*inv;
    atomicAdd(&scnt[i0], 1); atomicAdd(&scnt[i1], 1);
    atomicAdd(&scnt[i2], 1); atomicAdd(&scnt[i3], 1);
    float dsum = 0.f;
    for (int i = 0; i < 32; ++i) dsum += expf(row[i] - v0);
    float dinv = 1.f / dsum;
    for (int i = 0; i < 32; ++i) {
        float p = expf(row[i] - v0) * dinv;
#pragma unroll
        for (int o = 32; o >= 1; o >>= 1) p += __shfl_xor(p, o, 64);
        if ((tid & 63) == 0) atomicAdd(&simp[i], p);
    }
    __syncthreads();
    if (tid < 32) { atomicAdd(&imp[tid], simp[tid]); atomicAdd(&cnt[tid], scnt[tid]); }
}

__global__ void prefix_k(const int* __restrict__ cnt, int* __restrict__ poff,
                         int* __restrict__ ntp, int* __restrict__ t2e)
{
    if (threadIdx.x == 0) {
        int acc = 0;
        for (int e = 0; e < 32; ++e) {
            poff[e] = acc * 64;
            int pt = (cnt[e] + 63) >> 6;
            for (int t = 0; t < pt; ++t) t2e[acc + t] = e;
            acc += pt;
        }
        poff[32] = acc * 64;
        *ntp = acc;
    }
}

__global__ __launch_bounds__(256) void scatter_k(const int* __restrict__ rti,
    int* __restrict__ cnt2, const int* __restrict__ poff,
    int* __restrict__ slotb, int* __restrict__ r2s)
{
    int b = blockIdx.x * 256 + threadIdx.x;
#pragma unroll
    for (int j = 0; j < 4; ++j) {
        int e = rti[b * 4 + j];
        int p = atomicAdd(&cnt2[e], 1);
        int s = poff[e] + p;
        slotb[s] = b;
        r2s[b * 4 + j] = s;
    }
}

// =====================================================================
// combine top-4 expert outputs -> relu -> @p2_w(fp32) -> +b -> tanh
// =====================================================================
__global__ __launch_bounds__(256) void comb_p2_k(const half_t* __restrict__ ybuf,
    const int* __restrict__ r2s, const float* __restrict__ rtw,
    const float* __restrict__ p2w, const float* __restrict__ p2b, float* __restrict__ outp)
{
    __shared__ float lw[7 * 1024];
    int tid = threadIdx.x;
    for (int i = tid; i < 7168; i += 256) {
        int c = i >> 10, k = i & 1023;
        lw[i] = p2w[(size_t)k * 7 + c];
    }
    __syncthreads();
    int wid = tid >> 6, lane = tid & 63;
    int b = blockIdx.x * 4 + wid;
    int s0 = r2s[b*4+0], s1_ = r2s[b*4+1], s2_ = r2s[b*4+2], s3_ = r2s[b*4+3];
    float w0 = rtw[b*4+0], w1 = rtw[b*4+1], w2 = rtw[b*4+2], w3 = rtw[b*4+3];
    float xm[16];
#pragma unroll
    for (int u = 0; u < 8; ++u) {
        int k = u * 128 + lane * 2;
        half2v y0 = *(const half2v*)(ybuf + (size_t)s0  * 1024 + k);
        half2v y1 = *(const half2v*)(ybuf + (size_t)s1_ * 1024 + k);
        half2v y2 = *(const half2v*)(ybuf + (size_t)s2_ * 1024 + k);
        half2v y3 = *(const half2v*)(ybuf + (size_t)s3_ * 1024 + k);
        float a  = w0*(float)y0[0] + w1*(float)y1[0] + w2*(float)y2[0] + w3*(float)y3[0];
        float bq = w0*(float)y0[1] + w1*(float)y1[1] + w2*(float)y2[1] + w3*(float)y3[1];
        xm[u*2]   = fmaxf(a, 0.f);
        xm[u*2+1] = fmaxf(bq, 0.f);
    }
    float p[7] = {0, 0, 0, 0, 0, 0, 0};
#pragma unroll
    for (int u = 0; u < 8; ++u) {
        int k = u * 128 + lane * 2;
#pragma unroll
        for (int c = 0; c < 7; ++c)
            p[c] += xm[u*2] * lw[c * 1024 + k] + xm[u*2+1] * lw[c * 1024 + k + 1];
    }
#pragma unroll
    for (int c = 0; c < 7; ++c) {
#pragma unroll
        for (int o = 32; o >= 1; o >>= 1) p[c] += __shfl_xor(p[c], o, 64);
    }
    if (lane == 0) {
#pragma unroll
        for (int c = 0; c < 7; ++c) outp[(size_t)b * 7 + c] = tanhf(p[c] + p2b[c]);
    }
}

__global__ void aux_k(const float* __restrict__ imp, const int* __restrict__ cnt,
                      float* __restrict__ outp)
{
    int t = threadIdx.x;
    float v = (t < 32) ? imp[t] * (float)cnt[t] : 0.f;
#pragma unroll
    for (int o = 32; o >= 1; o >>= 1) v += __shfl_xor(v, o, 64);
    if (t == 0) outp[0] = 32.f * v / (4096.f * 4096.f);
}

// =====================================================================
extern "C" void kernel_launch(void* const* d_in, const int* in_sizes, int n_in,
                              void* d_out, int out_size, void* d_ws, size_t ws_size,
                              hipStream_t stream)
{
    (void)in_sizes; (void)n_in; (void)out_size; (void)ws_size;
    const float* obs        = (const float*)d_in[0];
    const float* obs_sensor = (const float*)d_in[2];
    const float* trunk_w    = (const float*)d_in[3];
    const float* trunk_b    = (const float*)d_in[4];
    const float* ln_g       = (const float*)d_in[5];
    const float* ln_b       = (const float*)d_in[6];
    const float* se1_w      = (const float*)d_in[7];
    const float* se1_b      = (const float*)d_in[8];
    const float* se2_b      = (const float*)d_in[10];
    const float* fu1_b      = (const float*)d_in[12];
    const float* fu2_b      = (const float*)d_in[14];
    const float* p1_b       = (const float*)d_in[16];
    const float* g1_b       = (const float*)d_in[18];
    const float* g2_w       = (const float*)d_in[19];
    const float* g2_b       = (const float*)d_in[20];
    const float* e1_b       = (const float*)d_in[22];
    const float* e2_b       = (const float*)d_in[24];
    const float* p2_w       = (const float*)d_in[25];
    const float* p2_b       = (const float*)d_in[26];

    char* ws = (char*)d_ws;
    half_t* WT_TRUNK = (half_t*)(ws + OFF_WT_TRUNK);
    half_t* WT_SE2   = (half_t*)(ws + OFF_WT_SE2);
    half_t* WT_FU1   = (half_t*)(ws + OFF_WT_FU1);
    half_t* WT_FU2   = (half_t*)(ws + OFF_WT_FU2);
    half_t* WT_P1    = (half_t*)(ws + OFF_WT_P1);
    half_t* WT_G1    = (half_t*)(ws + OFF_WT_G1);
    half_t* WT_E1    = (half_t*)(ws + OFF_WT_E1);
    half_t* WT_E2    = (half_t*)(ws + OFF_WT_E2);
    float*  PART     = (float*)(ws + OFF_PART);
    half_t* YBUF     = (half_t*)(ws + OFF_YBUF);
    float*  S1buf    = (float*)(ws + OFF_S1);
    float*  H1buf    = (float*)(ws + OFF_H1);
    float*  SOUT     = (float*)(ws + OFF_SOUT);
    float*  HBUF     = (float*)(ws + OFF_HBUF);
    float*  H2buf    = (float*)(ws + OFF_H2);
    float*  XBUF     = (float*)(ws + OFF_XBUF);
    float*  GBUF     = (float*)(ws + OFF_GBUF);
    float*  LOGITS   = (float*)(ws + OFF_LOGITS);
    int*    RTI      = (int*)(ws + OFF_RTI);
    float*  RTW      = (float*)(ws + OFF_RTW);
    float*  IMP      = (float*)(ws + OFF_CTRL);
    int*    CNT      = (int*)(ws + OFF_CTRL + 128);
    int*    CNT2     = (int*)(ws + OFF_CTRL + 256);
    int*    POFF     = (int*)(ws + OFF_CTRL + 384);
    int*    NTP      = (int*)(ws + OFF_CTRL + 520);
    int*    T2E      = (int*)(ws + OFF_CTRL + 524);
    int*    SLOTB    = (int*)(ws + OFF_SLOTB);
    int*    R2S      = (int*)(ws + OFF_R2S);
    half_t* H1E      = (half_t*)(ws + OFF_H1E);

    hipMemsetAsync(ws + OFF_CTRL, 0, SZ_CTRL, stream);
    hipMemsetAsync(ws + OFF_SLOTB, 0xFF, (size_t)SLOTCAP * 4, stream);

    cvt_k<<<27464, 256, 0, stream>>>(trunk_w, (const float*)d_in[9], (const float*)d_in[11],
        (const float*)d_in[13], (const float*)d_in[15], (const float*)d_in[17],
        (const float*)d_in[21], (const float*)d_in[23], ws);

    // sensor layer1 (fp32 VALU, exact)
    se1_k<<<1024, 256, 0, stream>>>(obs_sensor, se1_w, se1_b, S1buf);
    // sensor layer2 (precision, split-K 4) -> SOUT fp32
    gemm_prec<0,1><<<dim3(64,4), 256, 0, stream>>>(S1buf, WT_SE2, nullptr, PART,
        1024, 1024, 32, 256, PLANE_SMALL);
    reduce4_k<0><<<1024, 256, 0, stream>>>(PART, se2_b, SOUT);
    // trunk GEMM (precision, split-K 8: 512 blocks = 2/CU with 80KB LDS)
    gemm_prec<0,1><<<dim3(64,8), 256, 0, stream>>>(obs, WT_TRUNK, nullptr, PART,
        39200, 39200, 1225, 256, PLANE_TRUNK);
    lnfuse_k<<<4096, 256, 0, stream>>>(PART, trunk_b, ln_g, ln_b, SOUT, HBUF);
    // fusion MLP (precision)
    gemm_prec<1,0><<<dim3(64,4), 256, 0, stream>>>(HBUF, WT_FU1, fu1_b, H1buf,
        256, 256, 8, 1024, PLANE_SMALL);
    gemm_prec<0,1><<<dim3(64,4), 256, 0, stream>>>(H1buf, WT_FU2, nullptr, PART,
        1024, 1024, 32, 256, PLANE_SMALL);
    reduce4_k<0><<<1024, 256, 0, stream>>>(PART, fu2_b, H2buf);
    // policy1 (precision)
    gemm_prec<1,0><<<dim3(64,4), 256, 0, stream>>>(H2buf, WT_P1, p1_b, XBUF,
        256, 256, 8, 1024, PLANE_SMALL);
    // gate MLP (precision)
    gemm_prec<0,1><<<dim3(64,4), 256, 0, stream>>>(XBUF, WT_G1, nullptr, PART,
        1024, 1024, 32, 256, PLANE_SMALL);
    reduce4_k<1><<<1024, 256, 0, stream>>>(PART, g1_b, GBUF);
    logits_k<<<512, 256, 0, stream>>>(GBUF, g2_w, g2_b, LOGITS);
    topk_k<<<16, 256, 0, stream>>>(LOGITS, RTI, RTW, IMP, CNT);
    prefix_k<<<1, 64, 0, stream>>>(CNT, POFF, NTP, T2E);
    scatter_k<<<16, 256, 0, stream>>>(RTI, CNT2, POFF, SLOTB, R2S);
    // sparse MoE (fp16)
    gemm_fast<1,1,1><<<dim3(MAXTILES,1), 256, 0, stream>>>(XBUF, WT_E1, e1_b, H1E,
        1024, 1024, 32, 256, SLOTB, T2E, NTP, 262144, 256);
    gemm_fast<0,2,0><<<dim3(MAXTILES,4), 256, 0, stream>>>(H1E, WT_E2, e2_b, YBUF,
        256, 256, 8, 1024, nullptr, T2E, NTP, 262144, 1024);
    comb_p2_k<<<1024, 256, 0, stream>>>(YBUF, R2S, RTW, p2_w, p2_b, (float*)d_out);
    aux_k<<<1, 64, 0, stream>>>(IMP, CNT, (float*)d_out + 28672);
}